// Round 3
// baseline (375.266 us; speedup 1.0000x reference)
//
#include <hip/hip_runtime.h>

// MLPLowRankPredictor: FastFood (B,H,P,G,H,S) low-rank weight perturbation + 3-layer MLP.
// N=2048 tokens. Z=128, X=32, H=128, Y=16.
// FF blocks: wd0: 0..31 (4 rows x 32 cols), bd0: 32, wd1: 33..160 (1 row each),
//            bd1: 161, wd2: 162..177 (1 row each), bd2: 178 (first 16 elems).
// R2b: fp16-packed LDS round trip (16 KB -> 10 blocks/CU vs 5), launch_bounds(64,3)
// on K2/K3 (VGPR<=168 -> 3 waves/SIMD), bias blocks computed ONCE (extra grid row
// writing to ws) instead of per-wave recompute; relu(part+bias) fused at read.
// (R2 fix: cvt_pkrtz returns __fp16 vector, not _Float16 vector.)

#define ZD 128
#define XD 32
#define HD 128
#define YD 16

typedef __fp16 f16x2 __attribute__((ext_vector_type(2)));

__device__ __forceinline__ void fwht128(float v[128]) {
#pragma unroll
  for (int s = 1; s < 128; s <<= 1) {
#pragma unroll
    for (int p = 0; p < 128; p++) {
      if ((p & s) == 0) {
        float a = v[p], b = v[p + s];
        v[p] = a + b;
        v[p + s] = a - b;
      }
    }
  }
}

__device__ __forceinline__ void load128(float v[128], const float* __restrict__ src) {
  const float4* s4 = (const float4*)src;
#pragma unroll
  for (int k = 0; k < 32; k++) {
    float4 f = s4[k];
    v[4 * k + 0] = f.x; v[4 * k + 1] = f.y; v[4 * k + 2] = f.z; v[4 * k + 3] = f.w;
  }
}

// v holds z on entry; on exit v = ffS * FWHT( ffG * perm( FWHT( ffB * z ) ) )
// (the final /128 applied by the consumer). Permutation round-trips LDS in
// packed fp16: [pair_idx][lane] uint32 layout -> writes & u16 reads both
// land 2 lanes/bank (free per m136).
__device__ __forceinline__ void ff_block(float v[128], f16x2* lds, int lane,
    const float* __restrict__ ffB, const float* __restrict__ ffG,
    const float* __restrict__ ffS, const int* __restrict__ ffP, int j) {
  const float* Bj = ffB + j * ZD;   // uniform -> s_load
  const float* Gj = ffG + j * ZD;
  const float* Sj = ffS + j * ZD;
  const int*   Pj = ffP + j * ZD;
#pragma unroll
  for (int k = 0; k < 128; k++) v[k] *= Bj[k];
  fwht128(v);
  __syncthreads();                              // WAR vs previous block's reads
#pragma unroll
  for (int k = 0; k < 64; k++)
    lds[k * 64 + lane] = __builtin_amdgcn_cvt_pkrtz(v[2 * k], v[2 * k + 1]);
  __syncthreads();
  const __fp16* hl = (const __fp16*)lds;
#pragma unroll
  for (int k = 0; k < 128; k++) {
    int p = Pj[k];                              // uniform
    v[k] = Gj[k] * (float)hl[(p >> 1) * 128 + lane * 2 + (p & 1)];
  }
  fwht128(v);
#pragma unroll
  for (int k = 0; k < 128; k++) v[k] *= Sj[k];
}

// K1: grid (32, 33). b<32: h1_part[t][4b..4b+3] = W0 row dot x + b0 + wdot/128
//     b==32: h1_bias[t][0..127] = bd0/128  (computed once, not per-wave)
__global__ __launch_bounds__(64) void k1_layer0(
    const float* __restrict__ x, const float* __restrict__ z,
    const float* __restrict__ W0, const float* __restrict__ b0,
    const float* __restrict__ ffB, const float* __restrict__ ffG,
    const float* __restrict__ ffS, const int* __restrict__ ffP,
    float* __restrict__ h1_part, float* __restrict__ h1_bias) {
  __shared__ f16x2 lds[64 * 64];   // 16 KB
  const int lane = threadIdx.x;
  const int tg = blockIdx.x;       // 0..31
  const int b  = blockIdx.y;       // 0..32 == FF block index directly
  const int t = tg * 64 + lane;

  float v[128];
  load128(v, z + (size_t)t * ZD);
  ff_block(v, lds, lane, ffB, ffG, ffS, ffP, b);

  if (b < 32) {
    float xi[32];
    const float4* x4 = (const float4*)(x + (size_t)t * XD);
#pragma unroll
    for (int k = 0; k < 8; k++) {
      float4 f = x4[k];
      xi[4 * k] = f.x; xi[4 * k + 1] = f.y; xi[4 * k + 2] = f.z; xi[4 * k + 3] = f.w;
    }
    float4 o;
    float* op = &o.x;
#pragma unroll
    for (int r = 0; r < 4; r++) {
      float aw = 0.f, ab = 0.f;
#pragma unroll
      for (int i = 0; i < 32; i++) {
        aw += v[r * 32 + i] * xi[i];
        ab += W0[(4 * b + r) * 32 + i] * xi[i];   // uniform -> s_load
      }
      op[r] = ab + b0[4 * b + r] + aw * (1.0f / 128.0f);
    }
    *(float4*)(h1_part + (size_t)t * HD + 4 * b) = o;
  } else {
    float4* o4 = (float4*)(h1_bias + (size_t)t * HD);
#pragma unroll
    for (int k = 0; k < 32; k++)
      o4[k] = make_float4(v[4 * k] * (1.0f / 128.0f), v[4 * k + 1] * (1.0f / 128.0f),
                          v[4 * k + 2] * (1.0f / 128.0f), v[4 * k + 3] * (1.0f / 128.0f));
  }
}

// K2: grid (32, 130). jr<128: h2_part[t][jr] (pre-relu, sans bd1).
//     jr==128: h2_bias = bd1/128. jr==129: bd2buf[t][0..15] = bd2/128 (for K3).
__global__ __launch_bounds__(64, 3) void k2_layer1(
    const float* __restrict__ z,
    const float* __restrict__ W1, const float* __restrict__ b1,
    const float* __restrict__ ffB, const float* __restrict__ ffG,
    const float* __restrict__ ffS, const int* __restrict__ ffP,
    const float* __restrict__ h1_part, const float* __restrict__ h1_bias,
    float* __restrict__ h2_part, float* __restrict__ h2_bias,
    float* __restrict__ bd2buf) {
  __shared__ f16x2 lds[64 * 64];   // 16 KB
  const int lane = threadIdx.x;
  const int tg = blockIdx.x;       // 0..31
  const int jr = blockIdx.y;       // 0..129
  const int t = tg * 64 + lane;
  const int j = (jr < 128) ? (33 + jr) : ((jr == 128) ? 161 : 178);

  float v[128];
  load128(v, z + (size_t)t * ZD);
  ff_block(v, lds, lane, ffB, ffG, ffS, ffP, j);

  if (jr < 128) {
    const float4* p4 = (const float4*)(h1_part + (size_t)t * HD);
    const float4* q4 = (const float4*)(h1_bias + (size_t)t * HD);
    const float* W1r = W1 + (size_t)jr * 128;    // uniform -> s_load
    float aw0 = 0.f, aw1 = 0.f, ab0 = 0.f, ab1 = 0.f;
#pragma unroll
    for (int k = 0; k < 32; k++) {
      float4 p = p4[k], q = q4[k];
      float e0 = fmaxf(p.x + q.x, 0.f), e1 = fmaxf(p.y + q.y, 0.f);
      float e2 = fmaxf(p.z + q.z, 0.f), e3 = fmaxf(p.w + q.w, 0.f);
      aw0 += v[4 * k + 0] * e0 + v[4 * k + 2] * e2;
      aw1 += v[4 * k + 1] * e1 + v[4 * k + 3] * e3;
      ab0 += W1r[4 * k + 0] * e0 + W1r[4 * k + 2] * e2;
      ab1 += W1r[4 * k + 1] * e1 + W1r[4 * k + 3] * e3;
    }
    h2_part[(size_t)t * HD + jr] = (ab0 + ab1) + b1[jr] + (aw0 + aw1) * (1.0f / 128.0f);
  } else if (jr == 128) {
    float4* o4 = (float4*)(h2_bias + (size_t)t * HD);
#pragma unroll
    for (int k = 0; k < 32; k++)
      o4[k] = make_float4(v[4 * k] * (1.0f / 128.0f), v[4 * k + 1] * (1.0f / 128.0f),
                          v[4 * k + 2] * (1.0f / 128.0f), v[4 * k + 3] * (1.0f / 128.0f));
  } else {
    float4* o4 = (float4*)(bd2buf + (size_t)t * YD);
#pragma unroll
    for (int k = 0; k < 4; k++)
      o4[k] = make_float4(v[4 * k] * (1.0f / 128.0f), v[4 * k + 1] * (1.0f / 128.0f),
                          v[4 * k + 2] * (1.0f / 128.0f), v[4 * k + 3] * (1.0f / 128.0f));
  }
}

// K3: grid (32, 16). out[t][b] = W2 row dot relu(h2) + b2 + (wd2 dot)/128 + bd2.
__global__ __launch_bounds__(64, 3) void k3_layer2(
    const float* __restrict__ z,
    const float* __restrict__ W2, const float* __restrict__ b2,
    const float* __restrict__ ffB, const float* __restrict__ ffG,
    const float* __restrict__ ffS, const int* __restrict__ ffP,
    const float* __restrict__ h2_part, const float* __restrict__ h2_bias,
    const float* __restrict__ bd2buf, float* __restrict__ out) {
  __shared__ f16x2 lds[64 * 64];   // 16 KB
  const int lane = threadIdx.x;
  const int tg = blockIdx.x;       // 0..31
  const int b  = blockIdx.y;       // 0..15
  const int t = tg * 64 + lane;

  float v[128];
  load128(v, z + (size_t)t * ZD);
  ff_block(v, lds, lane, ffB, ffG, ffS, ffP, 162 + b);

  const float4* p4 = (const float4*)(h2_part + (size_t)t * HD);
  const float4* q4 = (const float4*)(h2_bias + (size_t)t * HD);
  const float* W2r = W2 + (size_t)b * 128;       // uniform -> s_load
  float aw = 0.f, ab = 0.f;
#pragma unroll
  for (int k = 0; k < 32; k++) {
    float4 p = p4[k], q = q4[k];
    float e0 = fmaxf(p.x + q.x, 0.f), e1 = fmaxf(p.y + q.y, 0.f);
    float e2 = fmaxf(p.z + q.z, 0.f), e3 = fmaxf(p.w + q.w, 0.f);
    aw += v[4 * k] * e0 + v[4 * k + 1] * e1 + v[4 * k + 2] * e2 + v[4 * k + 3] * e3;
    ab += W2r[4 * k] * e0 + W2r[4 * k + 1] * e1 + W2r[4 * k + 2] * e2 + W2r[4 * k + 3] * e3;
  }
  out[(size_t)t * YD + b] = ab + b2[b] + aw * (1.0f / 128.0f) + bd2buf[(size_t)t * YD + b];
}

extern "C" void kernel_launch(void* const* d_in, const int* in_sizes, int n_in,
                              void* d_out, int out_size, void* d_ws, size_t ws_size,
                              hipStream_t stream) {
  const float* x  = (const float*)d_in[0];
  const float* z  = (const float*)d_in[1];
  const float* W0 = (const float*)d_in[2];
  const float* b0 = (const float*)d_in[3];
  const float* W1 = (const float*)d_in[4];
  const float* b1 = (const float*)d_in[5];
  const float* W2 = (const float*)d_in[6];
  const float* b2 = (const float*)d_in[7];
  const float* fB = (const float*)d_in[8];
  const float* fG = (const float*)d_in[9];
  const float* fS = (const float*)d_in[10];
  const int*   fP = (const int*)d_in[11];
  float* out = (float*)d_out;

  float* h1_part = (float*)d_ws;             // 2048*128 f32 = 1 MB
  float* h1_bias = h1_part + 2048 * 128;     // 1 MB
  float* h2_part = h1_bias + 2048 * 128;     // 1 MB
  float* h2_bias = h2_part + 2048 * 128;     // 1 MB
  float* bd2buf  = h2_bias + 2048 * 128;     // 2048*16 f32 = 128 KB

  k1_layer0<<<dim3(32, 33), 64, 0, stream>>>(x, z, W0, b0, fB, fG, fS, fP,
                                             h1_part, h1_bias);
  k2_layer1<<<dim3(32, 130), 64, 0, stream>>>(z, W1, b1, fB, fG, fS, fP,
                                              h1_part, h1_bias, h2_part, h2_bias, bd2buf);
  k3_layer2<<<dim3(32, 16), 64, 0, stream>>>(z, W2, b2, fB, fG, fS, fP,
                                             h2_part, h2_bias, bd2buf, out);
}

// Round 4
// 196.783 us; speedup vs baseline: 1.9070x; 1.9070x over previous
//
#include <hip/hip_runtime.h>

// MLPLowRankPredictor: FastFood (B,H,P,G,H,S) low-rank weight perturbation + 3-layer MLP.
// N=2048 tokens. Z=128, X=32, H=128, Y=16.
// FF blocks: wd0: 0..31 (4 rows x 32 cols), bd0: 32, wd1: 33..160 (1 row each),
//            bd1: 161, wd2: 162..177 (1 row each), bd2: 178 (first 16 elems).
// R4: fp16-packed LDS (16 KB) + bias dedup (from R2b), but DEFAULT launch bounds:
// R3 showed __launch_bounds__(64,3) (VGPR cap 168 < 128-float live array + temps)
// spills the whole v[] to scratch (680 MB HBM traffic, 10% VALUBusy). 2 waves/SIMD
// is the max for this structure; occupancy target 25% (8 waves/CU), LDS cap 10/CU.
// K1 now streams x as transient float4 in the dot (no resident xi[32]).

#define ZD 128
#define XD 32
#define HD 128
#define YD 16

typedef __fp16 f16x2 __attribute__((ext_vector_type(2)));

__device__ __forceinline__ void fwht128(float v[128]) {
#pragma unroll
  for (int s = 1; s < 128; s <<= 1) {
#pragma unroll
    for (int p = 0; p < 128; p++) {
      if ((p & s) == 0) {
        float a = v[p], b = v[p + s];
        v[p] = a + b;
        v[p + s] = a - b;
      }
    }
  }
}

__device__ __forceinline__ void load128(float v[128], const float* __restrict__ src) {
  const float4* s4 = (const float4*)src;
#pragma unroll
  for (int k = 0; k < 32; k++) {
    float4 f = s4[k];
    v[4 * k + 0] = f.x; v[4 * k + 1] = f.y; v[4 * k + 2] = f.z; v[4 * k + 3] = f.w;
  }
}

// v holds z on entry; on exit v = ffS * FWHT( ffG * perm( FWHT( ffB * z ) ) )
// (final /128 applied by consumer). Permutation round-trips LDS in packed fp16:
// [pair_idx][lane] layout -> writes & u16 reads both 2 lanes/bank (free, m136).
__device__ __forceinline__ void ff_block(float v[128], f16x2* lds, int lane,
    const float* __restrict__ ffB, const float* __restrict__ ffG,
    const float* __restrict__ ffS, const int* __restrict__ ffP, int j) {
  const float* Bj = ffB + j * ZD;   // uniform -> s_load
  const float* Gj = ffG + j * ZD;
  const float* Sj = ffS + j * ZD;
  const int*   Pj = ffP + j * ZD;
#pragma unroll
  for (int k = 0; k < 128; k++) v[k] *= Bj[k];
  fwht128(v);
  __syncthreads();                              // WAR vs previous block's reads
#pragma unroll
  for (int k = 0; k < 64; k++)
    lds[k * 64 + lane] = __builtin_amdgcn_cvt_pkrtz(v[2 * k], v[2 * k + 1]);
  __syncthreads();
  const __fp16* hl = (const __fp16*)lds;
#pragma unroll
  for (int k = 0; k < 128; k++) {
    int p = Pj[k];                              // uniform
    v[k] = Gj[k] * (float)hl[(p >> 1) * 128 + lane * 2 + (p & 1)];
  }
  fwht128(v);
#pragma unroll
  for (int k = 0; k < 128; k++) v[k] *= Sj[k];
}

// K1: grid (32, 33). b<32: h1_part[t][4b..4b+3] = W0 rows dot x + b0 + wdot/128
//     b==32: h1_bias[t][:] = bd0/128 (computed once)
__global__ __launch_bounds__(64) void k1_layer0(
    const float* __restrict__ x, const float* __restrict__ z,
    const float* __restrict__ W0, const float* __restrict__ b0,
    const float* __restrict__ ffB, const float* __restrict__ ffG,
    const float* __restrict__ ffS, const int* __restrict__ ffP,
    float* __restrict__ h1_part, float* __restrict__ h1_bias) {
  __shared__ f16x2 lds[64 * 64];   // 16 KB
  const int lane = threadIdx.x;
  const int tg = blockIdx.x;       // 0..31
  const int b  = blockIdx.y;       // 0..32 == FF block index directly
  const int t = tg * 64 + lane;

  float v[128];
  load128(v, z + (size_t)t * ZD);
  ff_block(v, lds, lane, ffB, ffG, ffS, ffP, b);

  if (b < 32) {
    // stream x as transient float4 (no resident xi[32] -> lower VGPR peak)
    const float4* x4 = (const float4*)(x + (size_t)t * XD);
    float aw[4] = {0.f, 0.f, 0.f, 0.f}, ab[4] = {0.f, 0.f, 0.f, 0.f};
#pragma unroll
    for (int k = 0; k < 8; k++) {
      float4 f = x4[k];
#pragma unroll
      for (int r = 0; r < 4; r++) {
        aw[r] += v[r * 32 + 4 * k] * f.x + v[r * 32 + 4 * k + 1] * f.y +
                 v[r * 32 + 4 * k + 2] * f.z + v[r * 32 + 4 * k + 3] * f.w;
        const float* W0r = W0 + (4 * b + r) * 32 + 4 * k;   // uniform -> s_load
        ab[r] += W0r[0] * f.x + W0r[1] * f.y + W0r[2] * f.z + W0r[3] * f.w;
      }
    }
    float4 o;
    o.x = ab[0] + b0[4 * b + 0] + aw[0] * (1.0f / 128.0f);
    o.y = ab[1] + b0[4 * b + 1] + aw[1] * (1.0f / 128.0f);
    o.z = ab[2] + b0[4 * b + 2] + aw[2] * (1.0f / 128.0f);
    o.w = ab[3] + b0[4 * b + 3] + aw[3] * (1.0f / 128.0f);
    *(float4*)(h1_part + (size_t)t * HD + 4 * b) = o;
  } else {
    float4* o4 = (float4*)(h1_bias + (size_t)t * HD);
#pragma unroll
    for (int k = 0; k < 32; k++)
      o4[k] = make_float4(v[4 * k] * (1.0f / 128.0f), v[4 * k + 1] * (1.0f / 128.0f),
                          v[4 * k + 2] * (1.0f / 128.0f), v[4 * k + 3] * (1.0f / 128.0f));
  }
}

// K2: grid (32, 130). jr<128: h2_part[t][jr] (pre-relu, sans bd1).
//     jr==128: h2_bias = bd1/128. jr==129: bd2buf[t][0..15] = bd2/128 (for K3).
__global__ __launch_bounds__(64) void k2_layer1(
    const float* __restrict__ z,
    const float* __restrict__ W1, const float* __restrict__ b1,
    const float* __restrict__ ffB, const float* __restrict__ ffG,
    const float* __restrict__ ffS, const int* __restrict__ ffP,
    const float* __restrict__ h1_part, const float* __restrict__ h1_bias,
    float* __restrict__ h2_part, float* __restrict__ h2_bias,
    float* __restrict__ bd2buf) {
  __shared__ f16x2 lds[64 * 64];   // 16 KB
  const int lane = threadIdx.x;
  const int tg = blockIdx.x;       // 0..31
  const int jr = blockIdx.y;       // 0..129
  const int t = tg * 64 + lane;
  const int j = (jr < 128) ? (33 + jr) : ((jr == 128) ? 161 : 178);

  float v[128];
  load128(v, z + (size_t)t * ZD);
  ff_block(v, lds, lane, ffB, ffG, ffS, ffP, j);

  if (jr < 128) {
    const float4* p4 = (const float4*)(h1_part + (size_t)t * HD);
    const float4* q4 = (const float4*)(h1_bias + (size_t)t * HD);
    const float* W1r = W1 + (size_t)jr * 128;    // uniform -> s_load
    float aw0 = 0.f, aw1 = 0.f, ab0 = 0.f, ab1 = 0.f;
#pragma unroll
    for (int k = 0; k < 32; k++) {
      float4 p = p4[k], q = q4[k];
      float e0 = fmaxf(p.x + q.x, 0.f), e1 = fmaxf(p.y + q.y, 0.f);
      float e2 = fmaxf(p.z + q.z, 0.f), e3 = fmaxf(p.w + q.w, 0.f);
      aw0 += v[4 * k + 0] * e0 + v[4 * k + 2] * e2;
      aw1 += v[4 * k + 1] * e1 + v[4 * k + 3] * e3;
      ab0 += W1r[4 * k + 0] * e0 + W1r[4 * k + 2] * e2;
      ab1 += W1r[4 * k + 1] * e1 + W1r[4 * k + 3] * e3;
    }
    h2_part[(size_t)t * HD + jr] = (ab0 + ab1) + b1[jr] + (aw0 + aw1) * (1.0f / 128.0f);
  } else if (jr == 128) {
    float4* o4 = (float4*)(h2_bias + (size_t)t * HD);
#pragma unroll
    for (int k = 0; k < 32; k++)
      o4[k] = make_float4(v[4 * k] * (1.0f / 128.0f), v[4 * k + 1] * (1.0f / 128.0f),
                          v[4 * k + 2] * (1.0f / 128.0f), v[4 * k + 3] * (1.0f / 128.0f));
  } else {
    float4* o4 = (float4*)(bd2buf + (size_t)t * YD);
#pragma unroll
    for (int k = 0; k < 4; k++)
      o4[k] = make_float4(v[4 * k] * (1.0f / 128.0f), v[4 * k + 1] * (1.0f / 128.0f),
                          v[4 * k + 2] * (1.0f / 128.0f), v[4 * k + 3] * (1.0f / 128.0f));
  }
}

// K3: grid (32, 16). out[t][b] = W2 row dot relu(h2) + b2 + (wd2 dot)/128 + bd2.
__global__ __launch_bounds__(64) void k3_layer2(
    const float* __restrict__ z,
    const float* __restrict__ W2, const float* __restrict__ b2,
    const float* __restrict__ ffB, const float* __restrict__ ffG,
    const float* __restrict__ ffS, const int* __restrict__ ffP,
    const float* __restrict__ h2_part, const float* __restrict__ h2_bias,
    const float* __restrict__ bd2buf, float* __restrict__ out) {
  __shared__ f16x2 lds[64 * 64];   // 16 KB
  const int lane = threadIdx.x;
  const int tg = blockIdx.x;       // 0..31
  const int b  = blockIdx.y;       // 0..15
  const int t = tg * 64 + lane;

  float v[128];
  load128(v, z + (size_t)t * ZD);
  ff_block(v, lds, lane, ffB, ffG, ffS, ffP, 162 + b);

  const float4* p4 = (const float4*)(h2_part + (size_t)t * HD);
  const float4* q4 = (const float4*)(h2_bias + (size_t)t * HD);
  const float* W2r = W2 + (size_t)b * 128;       // uniform -> s_load
  float aw = 0.f, ab = 0.f;
#pragma unroll
  for (int k = 0; k < 32; k++) {
    float4 p = p4[k], q = q4[k];
    float e0 = fmaxf(p.x + q.x, 0.f), e1 = fmaxf(p.y + q.y, 0.f);
    float e2 = fmaxf(p.z + q.z, 0.f), e3 = fmaxf(p.w + q.w, 0.f);
    aw += v[4 * k] * e0 + v[4 * k + 1] * e1 + v[4 * k + 2] * e2 + v[4 * k + 3] * e3;
    ab += W2r[4 * k] * e0 + W2r[4 * k + 1] * e1 + W2r[4 * k + 2] * e2 + W2r[4 * k + 3] * e3;
  }
  out[(size_t)t * YD + b] = ab + b2[b] + aw * (1.0f / 128.0f) + bd2buf[(size_t)t * YD + b];
}

extern "C" void kernel_launch(void* const* d_in, const int* in_sizes, int n_in,
                              void* d_out, int out_size, void* d_ws, size_t ws_size,
                              hipStream_t stream) {
  const float* x  = (const float*)d_in[0];
  const float* z  = (const float*)d_in[1];
  const float* W0 = (const float*)d_in[2];
  const float* b0 = (const float*)d_in[3];
  const float* W1 = (const float*)d_in[4];
  const float* b1 = (const float*)d_in[5];
  const float* W2 = (const float*)d_in[6];
  const float* b2 = (const float*)d_in[7];
  const float* fB = (const float*)d_in[8];
  const float* fG = (const float*)d_in[9];
  const float* fS = (const float*)d_in[10];
  const int*   fP = (const int*)d_in[11];
  float* out = (float*)d_out;

  float* h1_part = (float*)d_ws;             // 2048*128 f32 = 1 MB
  float* h1_bias = h1_part + 2048 * 128;     // 1 MB
  float* h2_part = h1_bias + 2048 * 128;     // 1 MB
  float* h2_bias = h2_part + 2048 * 128;     // 1 MB
  float* bd2buf  = h2_bias + 2048 * 128;     // 2048*16 f32 = 128 KB

  k1_layer0<<<dim3(32, 33), 64, 0, stream>>>(x, z, W0, b0, fB, fG, fS, fP,
                                             h1_part, h1_bias);
  k2_layer1<<<dim3(32, 130), 64, 0, stream>>>(z, W1, b1, fB, fG, fS, fP,
                                              h1_part, h1_bias, h2_part, h2_bias, bd2buf);
  k3_layer2<<<dim3(32, 16), 64, 0, stream>>>(z, W2, b2, fB, fG, fS, fP,
                                             h2_part, h2_bias, bd2buf, out);
}

// Round 5
// 194.624 us; speedup vs baseline: 1.9282x; 1.0111x over previous
//
#include <hip/hip_runtime.h>

// MLPLowRankPredictor: FastFood (B,H,P,G,H,S) low-rank weight perturbation + 3-layer MLP.
// N=2048 tokens. Z=128, X=32, H=128, Y=16.
// FF blocks: wd0: 0..31 (4 rows x 32 cols), bd0: 32, wd1: 33..160 (1 row each),
//            bd1: 161, wd2: 162..177 (1 row each), bd2: 178 (first 16 elems).
// R5: TWO LANES PER TOKEN. Lane L: tok=L>>1 (32 tokens/wave), h=L&1 holds elements
// h*64..h*64+63. FWHT128 = 6 in-register stages (s=1..32, within-half) + cross-lane
// stage 64 via shfl_xor(.,1)+fma(sgn). Halves VGPR live-set (R4: 128-float array ->
// 132 VGPR, 3 waves/SIMD cap, 21% VALUBusy); doubles grid to 8320 waves for K2.
// B/G/S/P now per-lane VECTOR loads (2 distinct addrs/instr, L2-hot) -- kills the
// s_load latency serialization seen in R4. LDS perm round-trip: 8KB fp16 [e/2][tok],
// word bank = tok%32 -> 2-way on writes AND reads = free (m136).

#define ZD 128
#define XD 32
#define HD 128
#define YD 16

typedef __fp16 f16x2 __attribute__((ext_vector_type(2)));

// 6 within-half stages (span 1..32) then cross-lane stage (span 64).
__device__ __forceinline__ void fwht_split(float u[64], float sgn) {
#pragma unroll
  for (int s = 1; s < 64; s <<= 1) {
#pragma unroll
    for (int p = 0; p < 64; p++) {
      if ((p & s) == 0) {
        float a = u[p], b = u[p + s];
        u[p] = a + b;
        u[p + s] = a - b;
      }
    }
  }
#pragma unroll
  for (int k = 0; k < 64; k++) {
    float t = __shfl_xor(u[k], 1);      // partner half's value
    u[k] = fmaf(sgn, u[k], t);          // h=0: u+t ; h=1: t-u
  }
}

// u = lane's half of z on entry; on exit u = lane's half of
// ffS * FWHT( ffG * perm( FWHT( ffB * z ) ) )   (final /128 by consumer).
__device__ __forceinline__ void ff_block2(float u[64], f16x2* lds, int tok, int h,
    float sgn, const float* __restrict__ ffB, const float* __restrict__ ffG,
    const float* __restrict__ ffS, const int* __restrict__ ffP, int j) {
  const float4* B4 = (const float4*)(ffB + j * ZD + h * 64);
  const float4* G4 = (const float4*)(ffG + j * ZD + h * 64);
  const float4* S4 = (const float4*)(ffS + j * ZD + h * 64);
  const int4*   P4 = (const int4*)(ffP + j * ZD + h * 64);
#pragma unroll
  for (int c = 0; c < 16; c++) {
    float4 f = B4[c];
    u[4 * c + 0] *= f.x; u[4 * c + 1] *= f.y; u[4 * c + 2] *= f.z; u[4 * c + 3] *= f.w;
  }
  fwht_split(u, sgn);
  __syncthreads();                       // WAR vs previous block's reads
#pragma unroll
  for (int k = 0; k < 64; k += 2)        // row = e/2 = h*32 + k/2 ; [row][tok]
    lds[(h * 32 + (k >> 1)) * 32 + tok] = __builtin_amdgcn_cvt_pkrtz(u[k], u[k + 1]);
  __syncthreads();
  const __fp16* hl = (const __fp16*)lds;
#pragma unroll
  for (int c = 0; c < 16; c++) {
    int4 p = P4[c];
    float4 g = G4[c];
    u[4 * c + 0] = g.x * (float)hl[(p.x >> 1) * 64 + tok * 2 + (p.x & 1)];
    u[4 * c + 1] = g.y * (float)hl[(p.y >> 1) * 64 + tok * 2 + (p.y & 1)];
    u[4 * c + 2] = g.z * (float)hl[(p.z >> 1) * 64 + tok * 2 + (p.z & 1)];
    u[4 * c + 3] = g.w * (float)hl[(p.w >> 1) * 64 + tok * 2 + (p.w & 1)];
  }
  fwht_split(u, sgn);
#pragma unroll
  for (int c = 0; c < 16; c++) {
    float4 f = S4[c];
    u[4 * c + 0] *= f.x; u[4 * c + 1] *= f.y; u[4 * c + 2] *= f.z; u[4 * c + 3] *= f.w;
  }
}

__device__ __forceinline__ void load_half(float u[64], const float* __restrict__ src) {
  const float4* s4 = (const float4*)src;
#pragma unroll
  for (int c = 0; c < 16; c++) {
    float4 f = s4[c];
    u[4 * c + 0] = f.x; u[4 * c + 1] = f.y; u[4 * c + 2] = f.z; u[4 * c + 3] = f.w;
  }
}

// K1: grid (64, 33). b<32: lane h computes rows 4b+2h, 4b+2h+1 of h1_part.
//     b==32: h1_bias[t][half] = bd0/128.
__global__ __launch_bounds__(64) void k1_layer0(
    const float* __restrict__ x, const float* __restrict__ z,
    const float* __restrict__ W0, const float* __restrict__ b0,
    const float* __restrict__ ffB, const float* __restrict__ ffG,
    const float* __restrict__ ffS, const int* __restrict__ ffP,
    float* __restrict__ h1_part, float* __restrict__ h1_bias) {
  __shared__ f16x2 lds[64 * 32];         // 8 KB
  const int lane = threadIdx.x;
  const int tok = lane >> 1, h = lane & 1;
  const float sgn = h ? -1.f : 1.f;
  const int b = blockIdx.y;              // 0..32 == FF block index
  const int t = blockIdx.x * 32 + tok;

  float u[64];
  load_half(u, z + (size_t)t * ZD + h * 64);
  ff_block2(u, lds, tok, h, sgn, ffB, ffG, ffS, ffP, b);

  if (b < 32) {
    // lane's half holds rows (4b+2h, 4b+2h+1), 32 cols each; needs full x[t,0..32)
    const float4* x4 = (const float4*)(x + (size_t)t * XD);
    const int r0 = 4 * b + 2 * h;
    const float4* W0a = (const float4*)(W0 + (size_t)r0 * XD);
    const float4* W0b = (const float4*)(W0 + (size_t)(r0 + 1) * XD);
    float aw0 = 0.f, aw1 = 0.f, ab0 = 0.f, ab1 = 0.f;
#pragma unroll
    for (int c = 0; c < 8; c++) {
      float4 f = x4[c];
      aw0 += u[4 * c + 0] * f.x + u[4 * c + 1] * f.y + u[4 * c + 2] * f.z + u[4 * c + 3] * f.w;
      aw1 += u[32 + 4 * c + 0] * f.x + u[32 + 4 * c + 1] * f.y + u[32 + 4 * c + 2] * f.z + u[32 + 4 * c + 3] * f.w;
      float4 wa = W0a[c], wb = W0b[c];
      ab0 += wa.x * f.x + wa.y * f.y + wa.z * f.z + wa.w * f.w;
      ab1 += wb.x * f.x + wb.y * f.y + wb.z * f.z + wb.w * f.w;
    }
    float2 o;
    o.x = ab0 + b0[r0] + aw0 * (1.0f / 128.0f);
    o.y = ab1 + b0[r0 + 1] + aw1 * (1.0f / 128.0f);
    *(float2*)(h1_part + (size_t)t * HD + r0) = o;
  } else {
    float4* o4 = (float4*)(h1_bias + (size_t)t * HD + h * 64);
#pragma unroll
    for (int c = 0; c < 16; c++)
      o4[c] = make_float4(u[4 * c] * (1.0f / 128.0f), u[4 * c + 1] * (1.0f / 128.0f),
                          u[4 * c + 2] * (1.0f / 128.0f), u[4 * c + 3] * (1.0f / 128.0f));
  }
}

// K2: grid (64, 130). jr<128: h2_part[t][jr] (pre-relu, sans bd1).
//     jr==128: h2_bias = bd1/128. jr==129: bd2buf[t][0..15] = bd2/128.
__global__ __launch_bounds__(64) void k2_layer1(
    const float* __restrict__ z,
    const float* __restrict__ W1, const float* __restrict__ b1,
    const float* __restrict__ ffB, const float* __restrict__ ffG,
    const float* __restrict__ ffS, const int* __restrict__ ffP,
    const float* __restrict__ h1_part, const float* __restrict__ h1_bias,
    float* __restrict__ h2_part, float* __restrict__ h2_bias,
    float* __restrict__ bd2buf) {
  __shared__ f16x2 lds[64 * 32];         // 8 KB
  const int lane = threadIdx.x;
  const int tok = lane >> 1, h = lane & 1;
  const float sgn = h ? -1.f : 1.f;
  const int jr = blockIdx.y;             // 0..129
  const int t = blockIdx.x * 32 + tok;
  const int j = (jr < 128) ? (33 + jr) : ((jr == 128) ? 161 : 178);

  float u[64];
  load_half(u, z + (size_t)t * ZD + h * 64);
  ff_block2(u, lds, tok, h, sgn, ffB, ffG, ffS, ffP, j);

  if (jr < 128) {
    // e1 = relu(h1_part + h1_bias), lane's half; dot with u and with W1 row half
    const float4* p4 = (const float4*)(h1_part + (size_t)t * HD + h * 64);
    const float4* q4 = (const float4*)(h1_bias + (size_t)t * HD + h * 64);
    const float4* W14 = (const float4*)(W1 + (size_t)jr * HD + h * 64);
    float aw = 0.f, ab = 0.f;
#pragma unroll
    for (int c = 0; c < 16; c++) {
      float4 p = p4[c], q = q4[c], w = W14[c];
      float e0 = fmaxf(p.x + q.x, 0.f), e1 = fmaxf(p.y + q.y, 0.f);
      float e2 = fmaxf(p.z + q.z, 0.f), e3 = fmaxf(p.w + q.w, 0.f);
      aw += u[4 * c] * e0 + u[4 * c + 1] * e1 + u[4 * c + 2] * e2 + u[4 * c + 3] * e3;
      ab += w.x * e0 + w.y * e1 + w.z * e2 + w.w * e3;
    }
    aw += __shfl_xor(aw, 1);             // combine halves
    ab += __shfl_xor(ab, 1);
    if (h == 0)
      h2_part[(size_t)t * HD + jr] = ab + b1[jr] + aw * (1.0f / 128.0f);
  } else if (jr == 128) {
    float4* o4 = (float4*)(h2_bias + (size_t)t * HD + h * 64);
#pragma unroll
    for (int c = 0; c < 16; c++)
      o4[c] = make_float4(u[4 * c] * (1.0f / 128.0f), u[4 * c + 1] * (1.0f / 128.0f),
                          u[4 * c + 2] * (1.0f / 128.0f), u[4 * c + 3] * (1.0f / 128.0f));
  } else {
    if (h == 0) {                        // bd2: elements 0..15 live in half 0
      float4* o4 = (float4*)(bd2buf + (size_t)t * YD);
#pragma unroll
      for (int c = 0; c < 4; c++)
        o4[c] = make_float4(u[4 * c] * (1.0f / 128.0f), u[4 * c + 1] * (1.0f / 128.0f),
                            u[4 * c + 2] * (1.0f / 128.0f), u[4 * c + 3] * (1.0f / 128.0f));
    }
  }
}

// K3: grid (64, 16). out[t][b] = W2 row dot relu(h2) + b2 + wd2dot/128 + bd2.
__global__ __launch_bounds__(64) void k3_layer2(
    const float* __restrict__ z,
    const float* __restrict__ W2, const float* __restrict__ b2,
    const float* __restrict__ ffB, const float* __restrict__ ffG,
    const float* __restrict__ ffS, const int* __restrict__ ffP,
    const float* __restrict__ h2_part, const float* __restrict__ h2_bias,
    const float* __restrict__ bd2buf, float* __restrict__ out) {
  __shared__ f16x2 lds[64 * 32];         // 8 KB
  const int lane = threadIdx.x;
  const int tok = lane >> 1, h = lane & 1;
  const float sgn = h ? -1.f : 1.f;
  const int b = blockIdx.y;              // 0..15
  const int t = blockIdx.x * 32 + tok;

  float u[64];
  load_half(u, z + (size_t)t * ZD + h * 64);
  ff_block2(u, lds, tok, h, sgn, ffB, ffG, ffS, ffP, 162 + b);

  const float4* p4 = (const float4*)(h2_part + (size_t)t * HD + h * 64);
  const float4* q4 = (const float4*)(h2_bias + (size_t)t * HD + h * 64);
  const float4* W24 = (const float4*)(W2 + (size_t)b * HD + h * 64);
  float aw = 0.f, ab = 0.f;
#pragma unroll
  for (int c = 0; c < 16; c++) {
    float4 p = p4[c], q = q4[c], w = W24[c];
    float e0 = fmaxf(p.x + q.x, 0.f), e1 = fmaxf(p.y + q.y, 0.f);
    float e2 = fmaxf(p.z + q.z, 0.f), e3 = fmaxf(p.w + q.w, 0.f);
    aw += u[4 * c] * e0 + u[4 * c + 1] * e1 + u[4 * c + 2] * e2 + u[4 * c + 3] * e3;
    ab += w.x * e0 + w.y * e1 + w.z * e2 + w.w * e3;
  }
  aw += __shfl_xor(aw, 1);
  ab += __shfl_xor(ab, 1);
  if (h == 0)
    out[(size_t)t * YD + b] = ab + b2[b] + aw * (1.0f / 128.0f) + bd2buf[(size_t)t * YD + b];
}

extern "C" void kernel_launch(void* const* d_in, const int* in_sizes, int n_in,
                              void* d_out, int out_size, void* d_ws, size_t ws_size,
                              hipStream_t stream) {
  const float* x  = (const float*)d_in[0];
  const float* z  = (const float*)d_in[1];
  const float* W0 = (const float*)d_in[2];
  const float* b0 = (const float*)d_in[3];
  const float* W1 = (const float*)d_in[4];
  const float* b1 = (const float*)d_in[5];
  const float* W2 = (const float*)d_in[6];
  const float* b2 = (const float*)d_in[7];
  const float* fB = (const float*)d_in[8];
  const float* fG = (const float*)d_in[9];
  const float* fS = (const float*)d_in[10];
  const int*   fP = (const int*)d_in[11];
  float* out = (float*)d_out;

  float* h1_part = (float*)d_ws;             // 2048*128 f32 = 1 MB
  float* h1_bias = h1_part + 2048 * 128;     // 1 MB
  float* h2_part = h1_bias + 2048 * 128;     // 1 MB
  float* h2_bias = h2_part + 2048 * 128;     // 1 MB
  float* bd2buf  = h2_bias + 2048 * 128;     // 2048*16 f32 = 128 KB

  k1_layer0<<<dim3(64, 33), 64, 0, stream>>>(x, z, W0, b0, fB, fG, fS, fP,
                                             h1_part, h1_bias);
  k2_layer1<<<dim3(64, 130), 64, 0, stream>>>(z, W1, b1, fB, fG, fS, fP,
                                              h1_part, h1_bias, h2_part, h2_bias, bd2buf);
  k3_layer2<<<dim3(64, 16), 64, 0, stream>>>(z, W2, b2, fB, fG, fS, fP,
                                             h2_part, h2_bias, bd2buf, out);
}